// Round 2
// baseline (160.362 us; speedup 1.0000x reference)
//
#include <hip/hip_runtime.h>

#define BATCH 2
#define N 1024
#define NBINS 22
#define TDIM 16
#define TSTR 20   // padded LDS row stride in floats: 80 B (16B-aligned rows, spreads bank bases)

__global__ __launch_bounds__(256) void te_enc(
    const float* __restrict__ coords,   // (B,N,3) f32
    const float* __restrict__ confp,    // (B,N)   f32
    const float* __restrict__ Wp,       // (22,16) f32
    const float* __restrict__ bp,       // (16)    f32
    const float* __restrict__ gp,       // (16)    f32
    const float* __restrict__ betap,    // (16)    f32
    float* __restrict__ out)            // (B,N,N,16) f32
{
    __shared__ __align__(16) float tbl[NBINS * TSTR];

    const int tid = threadIdx.x;
    const int blk = blockIdx.x;           // 0..2047 -> (batch, i)
    const int batch = blk >> 10;
    const int i = blk & (N - 1);

    // Precompute per-bin Linear+LayerNorm+ReLU rows (one thread per bin).
    // one_hot @ W just selects row `bin` of W, so the whole MLP head collapses
    // to a 22x16 table.
    if (tid < NBINS) {
        float h[TDIM];
        float sum = 0.f;
        #pragma unroll
        for (int d = 0; d < TDIM; ++d) {
            h[d] = Wp[tid * TDIM + d] + bp[d];
            sum += h[d];
        }
        const float mu = sum * (1.f / TDIM);
        float s2 = 0.f;
        #pragma unroll
        for (int d = 0; d < TDIM; ++d) {
            const float t = h[d] - mu;
            s2 += t * t;
        }
        const float rs = 1.f / sqrtf(s2 * (1.f / TDIM) + 1e-5f);
        #pragma unroll
        for (int d = 0; d < TDIM; ++d) {
            const float v = (h[d] - mu) * rs * gp[d] + betap[d];
            tbl[tid * TSTR + d] = fmaxf(v, 0.f);
        }
    }
    __syncthreads();

    const float xi = coords[(batch * N + i) * 3 + 0];
    const float yi = coords[(batch * N + i) * 3 + 1];
    const float zi = coords[(batch * N + i) * 3 + 2];
    const float ci = confp[batch * N + i];

    float* orow = out + (((size_t)batch * N + i) * N) * TDIM;
    const float* jc = coords + batch * N * 3;
    const float* jf = confp + batch * N;

    #pragma unroll
    for (int it = 0; it < 4; ++it) {
        const int j = tid + it * 256;
        const float xj = jc[j * 3 + 0];
        const float yj = jc[j * 3 + 1];
        const float zj = jc[j * 3 + 2];
        const float cj = jf[j];

        // Exact-f32 distance, matching numpy op order; *_rn blocks FMA contraction.
        const float dx = __fsub_rn(xi, xj);
        const float dy = __fsub_rn(yi, yj);
        const float dz = __fsub_rn(zi, zj);
        float s = __fmul_rn(dx, dx);
        s = __fadd_rn(s, __fmul_rn(dy, dy));
        s = __fadd_rn(s, __fmul_rn(dz, dz));
        s = __fadd_rn(s, 1e-8f);
        const float dist = __fsqrt_rn(s);

        // searchsorted(edges, dist, side='left') == count of edges strictly < dist.
        // numpy FLOAT_fill arange: edges[k] = (float)k * (float)(40.0/21.0) in f32.
        // edges[0]=0 < dist always (dist >= 1e-4), so start at 1.
        int idx = 1;
        #pragma unroll
        for (int k = 1; k <= 20; ++k) {
            const float ek = (float)k * (float)(40.0 / 21.0);
            idx += (ek < dist) ? 1 : 0;
        }
        int bin = idx < 20 ? idx : 20;                 // clip to NUM_BINS-2
        if (!(ci > 0.f && cj > 0.f)) bin = NBINS - 1;  // no-template bin
        const float cm = fminf(ci, cj);

        const float4* row = (const float4*)&tbl[bin * TSTR];
        const float4 r0 = row[0], r1 = row[1], r2 = row[2], r3 = row[3];

        float4 o0, o1, o2, o3;
        o0.x = r0.x * cm; o0.y = r0.y * cm; o0.z = r0.z * cm; o0.w = r0.w * cm;
        o1.x = r1.x * cm; o1.y = r1.y * cm; o1.z = r1.z * cm; o1.w = r1.w * cm;
        o2.x = r2.x * cm; o2.y = r2.y * cm; o2.z = r2.z * cm; o2.w = r2.w * cm;
        o3.x = r3.x * cm; o3.y = r3.y * cm; o3.z = r3.z * cm; o3.w = r3.w * cm;

        float4* dst = (float4*)(orow + (size_t)j * TDIM);
        dst[0] = o0;
        dst[1] = o1;
        dst[2] = o2;
        dst[3] = o3;
    }
}

extern "C" void kernel_launch(void* const* d_in, const int* in_sizes, int n_in,
                              void* d_out, int out_size, void* d_ws, size_t ws_size,
                              hipStream_t stream) {
    const float* coords = (const float*)d_in[0];
    const float* conf   = (const float*)d_in[1];
    const float* W      = (const float*)d_in[2];
    const float* b      = (const float*)d_in[3];
    const float* g      = (const float*)d_in[4];
    const float* beta   = (const float*)d_in[5];
    float* out          = (float*)d_out;

    te_enc<<<dim3(BATCH * N), dim3(256), 0, stream>>>(coords, conf, W, b, g, beta, out);
}

// Round 3
// 147.710 us; speedup vs baseline: 1.0857x; 1.0857x over previous
//
#include <hip/hip_runtime.h>

#define BATCH 2
#define N 1024
#define NBINS 22
#define TDIM 16
#define TSTR 20   // padded LDS table row stride in floats: 80 B (16B-aligned rows)

__global__ __launch_bounds__(256) void te_enc(
    const float* __restrict__ coords,   // (B,N,3) f32
    const float* __restrict__ confp,    // (B,N)   f32
    const float* __restrict__ Wp,       // (22,16) f32
    const float* __restrict__ bp,       // (16)    f32
    const float* __restrict__ gp,       // (16)    f32
    const float* __restrict__ betap,    // (16)    f32
    float* __restrict__ out)            // (B,N,N,16) f32
{
    __shared__ __align__(16) float tbl[NBINS * TSTR];   // 1.76 KB
    __shared__ float lx[N], ly[N], lz[N], lc[N];        // 16 KB

    const int tid = threadIdx.x;
    const int blk = blockIdx.x;           // 0..2047 -> (batch, i)
    const int batch = blk >> 10;
    const int i = blk & (N - 1);

    const float* jc = coords + batch * N * 3;
    const float* jf = confp + batch * N;

    // Stage the j-row coords/conf into LDS once (global loads done exactly once
    // per block; afterwards all per-j reads are LDS broadcasts).
    #pragma unroll
    for (int q = 0; q < 4; ++q) {
        const int j = tid + q * 256;
        lx[j] = jc[j * 3 + 0];
        ly[j] = jc[j * 3 + 1];
        lz[j] = jc[j * 3 + 2];
        lc[j] = jf[j];
    }

    // Precompute per-bin Linear+LayerNorm+ReLU rows (one thread per bin).
    // one_hot @ W selects row `bin` of W, so the MLP head collapses to 22x16.
    if (tid < NBINS) {
        float h[TDIM];
        float sum = 0.f;
        #pragma unroll
        for (int d = 0; d < TDIM; ++d) {
            h[d] = Wp[tid * TDIM + d] + bp[d];
            sum += h[d];
        }
        const float mu = sum * (1.f / TDIM);
        float s2 = 0.f;
        #pragma unroll
        for (int d = 0; d < TDIM; ++d) {
            const float t = h[d] - mu;
            s2 += t * t;
        }
        const float rs = 1.f / sqrtf(s2 * (1.f / TDIM) + 1e-5f);
        #pragma unroll
        for (int d = 0; d < TDIM; ++d) {
            const float v = (h[d] - mu) * rs * gp[d] + betap[d];
            tbl[tid * TSTR + d] = fmaxf(v, 0.f);
        }
    }
    __syncthreads();

    const float xi = coords[(batch * N + i) * 3 + 0];
    const float yi = coords[(batch * N + i) * 3 + 1];
    const float zi = coords[(batch * N + i) * 3 + 2];
    const float ci = confp[batch * N + i];

    // Lane-major coalesced stores: the output row is 4096 float4s; lane l of
    // wave w stores float4 index j_base*4 + 64*c + l (1 KB/instruction,
    // perfectly coalesced). That index corresponds to j = j_base + 16c + (l>>2),
    // sub-chunk l&3 — each j's bin is computed redundantly by 4 lanes (cheap).
    const int w  = tid >> 6;
    const int l  = tid & 63;
    const int lq = l >> 2;       // which of 16 j's in this chunk
    const int sub = l & 3;       // which float4 of the 16-float feature row

    float4* orow4 = (float4*)out + ((size_t)(batch * N + i)) * (N * TDIM / 4);

    #pragma unroll
    for (int it = 0; it < 4; ++it) {
        const int j_base = it * 256 + w * 64;
        #pragma unroll
        for (int c = 0; c < 4; ++c) {
            const int j = j_base + 16 * c + lq;
            const float xj = lx[j];
            const float yj = ly[j];
            const float zj = lz[j];
            const float cj = lc[j];

            // Exact-f32 distance, matching numpy op order; *_rn blocks FMA contraction.
            const float dx = __fsub_rn(xi, xj);
            const float dy = __fsub_rn(yi, yj);
            const float dz = __fsub_rn(zi, zj);
            float s = __fmul_rn(dx, dx);
            s = __fadd_rn(s, __fmul_rn(dy, dy));
            s = __fadd_rn(s, __fmul_rn(dz, dz));
            s = __fadd_rn(s, 1e-8f);
            const float dist = __fsqrt_rn(s);

            // searchsorted(edges, dist, side='left') = #edges strictly < dist.
            // numpy f32 arange: edges[k] = (float)k * (float)(40.0/21.0).
            int idx = 1;  // edges[0]=0 < dist always (dist >= 1e-4)
            #pragma unroll
            for (int k = 1; k <= 20; ++k) {
                const float ek = (float)k * (float)(40.0 / 21.0);
                idx += (ek < dist) ? 1 : 0;
            }
            int bin = idx < 20 ? idx : 20;                 // clip to NUM_BINS-2
            if (!(ci > 0.f && cj > 0.f)) bin = NBINS - 1;  // no-template bin
            const float cm = fminf(ci, cj);

            const float4 r = *(const float4*)&tbl[bin * TSTR + sub * 4];
            float4 o;
            o.x = r.x * cm; o.y = r.y * cm; o.z = r.z * cm; o.w = r.w * cm;

            orow4[j_base * 4 + 64 * c + l] = o;
        }
    }
}

extern "C" void kernel_launch(void* const* d_in, const int* in_sizes, int n_in,
                              void* d_out, int out_size, void* d_ws, size_t ws_size,
                              hipStream_t stream) {
    const float* coords = (const float*)d_in[0];
    const float* conf   = (const float*)d_in[1];
    const float* W      = (const float*)d_in[2];
    const float* b      = (const float*)d_in[3];
    const float* g      = (const float*)d_in[4];
    const float* beta   = (const float*)d_in[5];
    float* out          = (float*)d_out;

    te_enc<<<dim3(BATCH * N), dim3(256), 0, stream>>>(coords, conf, W, b, g, beta, out);
}

// Round 4
// 145.568 us; speedup vs baseline: 1.1016x; 1.0147x over previous
//
#include <hip/hip_runtime.h>

#define BATCH 2
#define N 1024
#define NBINS 22
#define TDIM 16
#define TSTR 20   // padded LDS table row stride in floats: 80 B (16B-aligned rows)

__global__ __launch_bounds__(256) void te_enc(
    const float* __restrict__ coords,   // (B,N,3) f32
    const float* __restrict__ confp,    // (B,N)   f32
    const float* __restrict__ Wp,       // (22,16) f32
    const float* __restrict__ bp,       // (16)    f32
    const float* __restrict__ gp,       // (16)    f32
    const float* __restrict__ betap,    // (16)    f32
    float* __restrict__ out)            // (B,N,N,16) f32
{
    __shared__ __align__(16) float tbl[NBINS * TSTR];   // 1.76 KB
    __shared__ float4 ljc[N];                           // 16 KB: (x,y,z,conf) per j

    const int tid = threadIdx.x;
    const int blk = blockIdx.x;           // 0..2047 -> (batch, i)
    const int batch = blk >> 10;
    const int i = blk & (N - 1);

    const float* jc = coords + batch * N * 3;
    const float* jf = confp + batch * N;

    // Stage j-row (x,y,z,conf) into LDS as float4 (one b128 read per pair later).
    #pragma unroll
    for (int q = 0; q < 4; ++q) {
        const int j = tid + q * 256;
        float4 v;
        v.x = jc[j * 3 + 0];
        v.y = jc[j * 3 + 1];
        v.z = jc[j * 3 + 2];
        v.w = jf[j];
        ljc[j] = v;
    }

    // Precompute per-bin Linear+LayerNorm+ReLU rows (one thread per bin).
    // one_hot @ W selects row `bin` of W, so the MLP head collapses to 22x16.
    if (tid < NBINS) {
        float h[TDIM];
        float sum = 0.f;
        #pragma unroll
        for (int d = 0; d < TDIM; ++d) {
            h[d] = Wp[tid * TDIM + d] + bp[d];
            sum += h[d];
        }
        const float mu = sum * (1.f / TDIM);
        float s2 = 0.f;
        #pragma unroll
        for (int d = 0; d < TDIM; ++d) {
            const float t = h[d] - mu;
            s2 += t * t;
        }
        const float rs = 1.f / sqrtf(s2 * (1.f / TDIM) + 1e-5f);
        #pragma unroll
        for (int d = 0; d < TDIM; ++d) {
            const float v = (h[d] - mu) * rs * gp[d] + betap[d];
            tbl[tid * TSTR + d] = fmaxf(v, 0.f);
        }
    }
    __syncthreads();

    const float xi = coords[(batch * N + i) * 3 + 0];
    const float yi = coords[(batch * N + i) * 3 + 1];
    const float zi = coords[(batch * N + i) * 3 + 2];
    const float ci = confp[batch * N + i];
    const bool ci_ok = (ci > 0.f);

    // Lane-major coalesced stores: lane l of wave w stores float4 index
    // j_base*4 + 64*c + l (1 KB/instruction). j = j_base + 16c + (l>>2),
    // sub = l&3; each j's bin computed redundantly by 4 lanes (now cheap).
    const int w   = tid >> 6;
    const int l   = tid & 63;
    const int lq  = l >> 2;
    const int sub = l & 3;

    float4* orow4 = (float4*)out + ((size_t)(batch * N + i)) * (N * TDIM / 4);
    const float EW = (float)(40.0 / 21.0);   // same edge expression as np.arange f32

    #pragma unroll
    for (int it = 0; it < 4; ++it) {
        const int j_base = it * 256 + w * 64;
        #pragma unroll
        for (int c = 0; c < 4; ++c) {
            const int j = j_base + 16 * c + lq;
            const float4 pj = ljc[j];

            // Exact-f32 distance, matching numpy op order; *_rn blocks contraction.
            const float dx = __fsub_rn(xi, pj.x);
            const float dy = __fsub_rn(yi, pj.y);
            const float dz = __fsub_rn(zi, pj.z);
            float s = __fmul_rn(dx, dx);
            s = __fadd_rn(s, __fmul_rn(dy, dy));
            s = __fadd_rn(s, __fmul_rn(dz, dz));
            s = __fadd_rn(s, 1e-8f);
            const float dist = __fsqrt_rn(s);

            // O(1) searchsorted(side='left'): estimate k0 = trunc(dist/EW), then
            // exact boundary compares at k0 and k0+1 against fl(k*EW) — identical
            // to the 20-compare scan (estimate error ~1e-5 << edge spacing 1.9).
            int k0 = (int)__fmul_rn(dist, 0.525f);
            k0 = k0 < 20 ? k0 : 20;
            const int c1 = (__fmul_rn((float)k0, EW) < dist) ? 1 : 0;
            const int c2 = (__fmul_rn((float)(k0 + 1), EW) < dist) ? 1 : 0;
            const int idx = k0 + c1 + c2;            // = 1 + #{k in [1,20]: e_k < dist}
            int bin = idx < 20 ? idx : 20;           // clip to NUM_BINS-2
            if (!(ci_ok && pj.w > 0.f)) bin = NBINS - 1;
            const float cm = fminf(ci, pj.w);

            const float4 r = *(const float4*)&tbl[bin * TSTR + sub * 4];
            float4 o;
            o.x = r.x * cm; o.y = r.y * cm; o.z = r.z * cm; o.w = r.w * cm;

            orow4[j_base * 4 + 64 * c + l] = o;
        }
    }
}

extern "C" void kernel_launch(void* const* d_in, const int* in_sizes, int n_in,
                              void* d_out, int out_size, void* d_ws, size_t ws_size,
                              hipStream_t stream) {
    const float* coords = (const float*)d_in[0];
    const float* conf   = (const float*)d_in[1];
    const float* W      = (const float*)d_in[2];
    const float* b      = (const float*)d_in[3];
    const float* g      = (const float*)d_in[4];
    const float* beta   = (const float*)d_in[5];
    float* out          = (float*)d_out;

    te_enc<<<dim3(BATCH * N), dim3(256), 0, stream>>>(coords, conf, W, b, g, beta, out);
}